// Round 10
// baseline (515.838 us; speedup 1.0000x reference)
//
#include <hip/hip_runtime.h>
#include <hip/hip_bf16.h>
#include <math.h>

#define NN 50000
#define NE 800000
#define NG 64
#define INC 128
#define HIDC 64
#define NH 4
#define HC1 256
#define NEG 0.2f
#define NB 256
#define CE (NE/NB)          // 3125 edges per hist block
#define NW (NN/2)           // 25000 packed u16-pair words

static __device__ __forceinline__ float lrelu(float x){ return x > 0.f ? x : NEG*x; }
static __device__ __forceinline__ float eluf(float x){ return x > 0.f ? x : expm1f(x); }
static __device__ __forceinline__ unsigned short f2bf(float x){
    unsigned u = __float_as_uint(x);
    unsigned r = u + 0x7fffu + ((u>>16)&1u);
    return (unsigned short)(r>>16);
}
static __device__ __forceinline__ float bf2f(unsigned short b){
    return __uint_as_float(((unsigned)b) << 16);
}

// ---------------- Phase A: per-block-chunk histogram (LDS, packed 2xu16) ----------------
__global__ __launch_bounds__(256) void k_hist(const int* __restrict__ ei, unsigned* __restrict__ hist)
{
    __shared__ unsigned h[NW];          // 100 KB
    int tid = threadIdx.x, b = blockIdx.x;
    for (int w = tid; w < NW; w += 256) h[w] = 0u;
    __syncthreads();
    const int* dsts = ei + NE + b*CE;
    for (int i = tid; i < CE; i += 256){
        int d = dsts[i];
        atomicAdd(&h[d>>1], 1u << (16*(d&1)));
    }
    __syncthreads();
    unsigned* out = hist + (size_t)b*NW;
    for (int w = tid; w < NW; w += 256) out[w] = h[w];
}

// ---------------- Phase B: column scan over blocks -> per-block u16 bases + node degree ----------------
__global__ __launch_bounds__(256) void k_colscan(const unsigned* __restrict__ hist,
                                                 unsigned short* __restrict__ bases,
                                                 int* __restrict__ deg)
{
    int n = blockIdx.x*256 + threadIdx.x;
    if (n >= NN) return;
    int w = n>>1, sh = 16*(n&1);
    unsigned run = 0;
    #pragma unroll 8
    for (int b = 0; b < NB; b++){
        unsigned c = (hist[(size_t)b*NW + w] >> sh) & 0xffffu;
        bases[(size_t)b*NN + n] = (unsigned short)run;
        run += c;
    }
    deg[n] = (int)run;
}

// ---------------- exclusive scan (3 kernels) ----------------
__global__ void k_scanA(const int* __restrict__ cnt, int* __restrict__ offs, int* __restrict__ bsum)
{
    __shared__ int s[256];
    int t = threadIdx.x;
    int i = blockIdx.x*256 + t;
    int v = (i < NN) ? cnt[i] : 0;
    s[t] = v; __syncthreads();
    #pragma unroll
    for (int d=1; d<256; d<<=1){
        int tv = (t>=d)? s[t-d] : 0; __syncthreads();
        s[t] += tv; __syncthreads();
    }
    if (i < NN) offs[i] = s[t] - v;
    if (t == 255) bsum[blockIdx.x] = s[255];
}

__global__ void k_scanB(int* __restrict__ bsum, int nb)
{
    __shared__ int s[256];
    int t = threadIdx.x;
    int v = (t < nb) ? bsum[t] : 0;
    s[t] = v; __syncthreads();
    #pragma unroll
    for (int d=1; d<256; d<<=1){
        int tv = (t>=d)? s[t-d] : 0; __syncthreads();
        s[t] += tv; __syncthreads();
    }
    if (t < nb) bsum[t] = s[t] - v;
}

__global__ void k_scanC(const int* __restrict__ bsum, int* __restrict__ offs)
{
    int t = threadIdx.x;
    int i = blockIdx.x*256 + t;
    if (i < NN) offs[i] += bsum[blockIdx.x];
    if (i == 0 && blockIdx.x == 0) offs[NN] = NE;
}

// ---------------- Phase C: place edges (LDS running rank, no global atomics) ----------------
__global__ __launch_bounds__(256) void k_place(const int* __restrict__ ei,
                                               const int* __restrict__ offs,
                                               const unsigned short* __restrict__ bases,
                                               int* __restrict__ csr)
{
    __shared__ unsigned h[NW];          // running ranks, packed
    int tid = threadIdx.x, b = blockIdx.x;
    for (int w = tid; w < NW; w += 256) h[w] = 0u;
    __syncthreads();
    const int* srcs = ei + b*CE;
    const int* dsts = ei + NE + b*CE;
    const unsigned short* myb = bases + (size_t)b*NN;
    for (int i = tid; i < CE; i += 256){
        int s = srcs[i], d = dsts[i];
        unsigned old = atomicAdd(&h[d>>1], 1u << (16*(d&1)));
        unsigned rank = (old >> (16*(d&1))) & 0xffffu;
        csr[(unsigned)offs[d] + (unsigned)myb[d] + rank] = s;
    }
}

// ---------------- graph sizes via binary search on sorted batch ----------------
__global__ void k_gcnt(const int* __restrict__ batch, int* __restrict__ gcnt)
{
    int g = threadIdx.x;
    if (g >= NG) return;
    int lo = 0, hi = NN;
    while (lo < hi){ int mid = (lo+hi)>>1; if (batch[mid] < g) lo = mid+1; else hi = mid; }
    int a = lo;
    lo = 0; hi = NN;
    while (lo < hi){ int mid = (lo+hi)>>1; if (batch[mid] < g+1) lo = mid+1; else hi = mid; }
    gcnt[g] = lo - a;
}

// ---------------- GEMM1: h1 = x@W1 (bf16 out), fused alpha_src/alpha_dst (fp32) ----------------
__global__ __launch_bounds__(256) void k_gemm1(
    const float* __restrict__ x, const float* __restrict__ W1,
    const float* __restrict__ aw_s, const float* __restrict__ aw_d,
    unsigned short* __restrict__ h1b, float* __restrict__ as1, float* __restrict__ ad1)
{
    __shared__ float Al[64][68];
    __shared__ float Bl[64][128];
    int tid = threadIdx.x;
    int r0 = blockIdx.x * 64;
    int c0 = blockIdx.y * 128;
    float acc[8][4];
    #pragma unroll
    for (int i=0;i<8;i++){
        #pragma unroll
        for (int j=0;j<4;j++) acc[i][j]=0.f;
    }

    for (int k0 = 0; k0 < INC; k0 += 64) {
        {   // stage A (64 rows x 64 k)
            int row = tid>>2, q = tid&3;
            int gr = r0 + row; if (gr >= NN) gr = NN-1;
            const float4* srcp = (const float4*)(x + (size_t)gr*INC + k0 + q*16);
            float4* dstp = (float4*)(&Al[row][q*16]);
            #pragma unroll
            for (int j=0;j<4;j++) dstp[j] = srcp[j];
        }
        {   // stage B (64 k x 128 cols)
            int kk = tid>>5, f = tid&31;
            #pragma unroll
            for (int p=0;p<8;p++){
                int k = kk + p*8;
                ((float4*)(&Bl[k][0]))[f] = ((const float4*)(W1 + (size_t)(k0+k)*HC1 + c0))[f];
            }
        }
        __syncthreads();
        int rg = tid>>5, cg = tid&31;
        #pragma unroll 4
        for (int k=0;k<64;k++){
            float4 b = ((const float4*)(&Bl[k][0]))[cg];
            #pragma unroll
            for (int i=0;i<8;i++){
                float a = Al[rg*8+i][k];
                acc[i][0] = fmaf(a, b.x, acc[i][0]);
                acc[i][1] = fmaf(a, b.y, acc[i][1]);
                acc[i][2] = fmaf(a, b.z, acc[i][2]);
                acc[i][3] = fmaf(a, b.w, acc[i][3]);
            }
        }
        __syncthreads();
    }
    int rg = tid>>5, cg = tid&31;
    int cbase = c0 + cg*4;
    int head = cbase >> 6;
    int cw = cbase & 63;
    float4 wsv = *(const float4*)(aw_s + head*HIDC + cw);
    float4 wdv = *(const float4*)(aw_d + head*HIDC + cw);
    #pragma unroll
    for (int i=0;i<8;i++){
        int gr = r0 + rg*8 + i;
        bool ok = gr < NN;
        float4 c4; c4.x=acc[i][0]; c4.y=acc[i][1]; c4.z=acc[i][2]; c4.w=acc[i][3];
        if (ok){
            ushort4 hb;
            hb.x = f2bf(c4.x); hb.y = f2bf(c4.y); hb.z = f2bf(c4.z); hb.w = f2bf(c4.w);
            *(ushort4*)(h1b + (size_t)gr*HC1 + cbase) = hb;
        }
        float ps = c4.x*wsv.x + c4.y*wsv.y + c4.z*wsv.z + c4.w*wsv.w;
        float pd = c4.x*wdv.x + c4.y*wdv.y + c4.z*wdv.z + c4.w*wdv.w;
        #pragma unroll
        for (int d=1; d<16; d<<=1){
            ps += __shfl_xor(ps, d);
            pd += __shfl_xor(pd, d);
        }
        if (((cg & 15) == 0) && ok){
            as1[gr*4 + head] = ps;
            ad1[gr*4 + head] = pd;
        }
    }
}

// ---------------- aggregation layer 1: hoisted edge weights, one wave per dst ----------------
__global__ __launch_bounds__(256) void k_agg1(
    const unsigned short* __restrict__ h1b, const float* __restrict__ as1, const float* __restrict__ ad1,
    const float* __restrict__ b1, const int* __restrict__ offs, const int* __restrict__ csr,
    float* __restrict__ h1o)
{
    int node = blockIdx.x*4 + (threadIdx.x>>6);
    if (node >= NN) return;
    int lane = threadIdx.x & 63;
    int hd = lane >> 4;
    float adv_l = ad1[node*4 + (lane&3)];   // head (lane&3) dst-logit, for hoisted p
    float4 acc; acc.x=acc.y=acc.z=acc.w=0.f;
    float ssum = 0.f;
    int base = offs[node], end = offs[node+1];
    for (int pos = base; pos < end; pos += 64){
        int nchunk = end - pos; if (nchunk > 64) nchunk = 64;
        int src_l = (lane < nchunk) ? csr[pos + lane] : 0;
        for (int sc = 0; sc*16 < nchunk; sc++){
            int srcv = __shfl(src_l, sc*16 + (lane>>2));
            float asv = as1[srcv*4 + (lane&3)];          // lane 4j+q: as of edge j, head q
            float p_l = expf(lrelu(asv + adv_l));        // hoisted: one exp per lane per 16 edges
            int m = nchunk - sc*16; if (m > 16) m = 16;
            if (m == 16){
                #pragma unroll
                for (int j=0;j<16;j++){
                    int srcj = __shfl(src_l, sc*16 + j);
                    float pj = __shfl(p_l, 4*j + hd);
                    ssum += pj;
                    ushort4 hb = *(const ushort4*)(h1b + (size_t)srcj*HC1 + lane*4);
                    acc.x = fmaf(pj, bf2f(hb.x), acc.x);
                    acc.y = fmaf(pj, bf2f(hb.y), acc.y);
                    acc.z = fmaf(pj, bf2f(hb.z), acc.z);
                    acc.w = fmaf(pj, bf2f(hb.w), acc.w);
                }
            } else {
                for (int j=0;j<m;j++){
                    int srcj = __shfl(src_l, sc*16 + j);
                    float pj = __shfl(p_l, 4*j + hd);
                    ssum += pj;
                    ushort4 hb = *(const ushort4*)(h1b + (size_t)srcj*HC1 + lane*4);
                    acc.x = fmaf(pj, bf2f(hb.x), acc.x);
                    acc.y = fmaf(pj, bf2f(hb.y), acc.y);
                    acc.z = fmaf(pj, bf2f(hb.z), acc.z);
                    acc.w = fmaf(pj, bf2f(hb.w), acc.w);
                }
            }
        }
    }
    {   // self loop (head hd)
        float p = expf(lrelu(as1[node*4 + hd] + ad1[node*4 + hd]));
        ssum += p;
        ushort4 hb = *(const ushort4*)(h1b + (size_t)node*HC1 + lane*4);
        acc.x = fmaf(p, bf2f(hb.x), acc.x);
        acc.y = fmaf(p, bf2f(hb.y), acc.y);
        acc.z = fmaf(p, bf2f(hb.z), acc.z);
        acc.w = fmaf(p, bf2f(hb.w), acc.w);
    }
    float inv = 1.f/(ssum + 1e-16f);
    float4 bv = ((const float4*)b1)[lane];
    float4 o;
    o.x = eluf(fmaf(acc.x, inv, bv.x));
    o.y = eluf(fmaf(acc.y, inv, bv.y));
    o.z = eluf(fmaf(acc.z, inv, bv.z));
    o.w = eluf(fmaf(acc.w, inv, bv.w));
    ((float4*)h1o)[(size_t)node*64 + lane] = o;
}

// ---------------- GEMM2: h2 = h1o@W2 (bf16 out), fused alpha (fp32) ----------------
__global__ __launch_bounds__(256) void k_gemm2(
    const float* __restrict__ h1o, const float* __restrict__ W2,
    const float* __restrict__ aw_s, const float* __restrict__ aw_d,
    unsigned short* __restrict__ h2b, float* __restrict__ as2, float* __restrict__ ad2)
{
    __shared__ float Al[64][68];
    __shared__ float Bl[64][64];
    int tid = threadIdx.x;
    int r0 = blockIdx.x * 64;
    float acc[4][4];
    #pragma unroll
    for (int i=0;i<4;i++){
        #pragma unroll
        for (int j=0;j<4;j++) acc[i][j]=0.f;
    }

    for (int k0 = 0; k0 < HC1; k0 += 64) {
        {   // stage A
            int row = tid>>2, q = tid&3;
            int gr = r0 + row; if (gr >= NN) gr = NN-1;
            const float4* srcp = (const float4*)(h1o + (size_t)gr*HC1 + k0 + q*16);
            float4* dstp = (float4*)(&Al[row][q*16]);
            #pragma unroll
            for (int j=0;j<4;j++) dstp[j] = srcp[j];
        }
        {   // stage B (64 k x 64 cols)
            int kk = tid>>4, f = tid&15;
            #pragma unroll
            for (int p=0;p<4;p++){
                int k = kk + p*16;
                ((float4*)(&Bl[k][0]))[f] = ((const float4*)(W2 + (size_t)(k0+k)*HIDC))[f];
            }
        }
        __syncthreads();
        int rg = tid>>4, cg = tid&15;
        #pragma unroll 4
        for (int k=0;k<64;k++){
            float4 b = ((const float4*)(&Bl[k][0]))[cg];
            #pragma unroll
            for (int i=0;i<4;i++){
                float a = Al[rg*4+i][k];
                acc[i][0] = fmaf(a, b.x, acc[i][0]);
                acc[i][1] = fmaf(a, b.y, acc[i][1]);
                acc[i][2] = fmaf(a, b.z, acc[i][2]);
                acc[i][3] = fmaf(a, b.w, acc[i][3]);
            }
        }
        __syncthreads();
    }
    int rg = tid>>4, cg = tid&15;
    float4 wsv = ((const float4*)aw_s)[cg];
    float4 wdv = ((const float4*)aw_d)[cg];
    #pragma unroll
    for (int i=0;i<4;i++){
        int gr = r0 + rg*4 + i;
        bool ok = gr < NN;
        float4 c4; c4.x=acc[i][0]; c4.y=acc[i][1]; c4.z=acc[i][2]; c4.w=acc[i][3];
        if (ok){
            ushort4 hb;
            hb.x = f2bf(c4.x); hb.y = f2bf(c4.y); hb.z = f2bf(c4.z); hb.w = f2bf(c4.w);
            *(ushort4*)(h2b + (size_t)gr*HIDC + cg*4) = hb;
        }
        float ps = c4.x*wsv.x + c4.y*wsv.y + c4.z*wsv.z + c4.w*wsv.w;
        float pd = c4.x*wdv.x + c4.y*wdv.y + c4.z*wdv.z + c4.w*wdv.w;
        #pragma unroll
        for (int d=1; d<16; d<<=1){
            ps += __shfl_xor(ps, d);
            pd += __shfl_xor(pd, d);
        }
        if (cg == 0 && ok){
            as2[gr] = ps;
            ad2[gr] = pd;
        }
    }
}

// ---------------- aggregation layer 2: 4 nodes per wave (16-lane groups), hoisted weights ----------------
// Group grp (lane>>4) owns node blk*16 + wave*4 + grp; lane gl (lane&15) owns channels 4gl..4gl+3.
// Full h2 row = 16 lanes x ushort4 = 128B. No cross-lane reduce needed; ssum replicated in-group.
__global__ __launch_bounds__(256) void k_agg2(
    const unsigned short* __restrict__ h2b, const float* __restrict__ as2, const float* __restrict__ ad2,
    const float* __restrict__ b2, const int* __restrict__ offs, const int* __restrict__ csr,
    const int* __restrict__ batch, float* __restrict__ pool)
{
    int tid = threadIdx.x;
    int lane = tid & 63;
    int gl = lane & 15;                     // lane-in-group
    int gb = lane & 48;                     // group base within wave (0,16,32,48)
    int node = blockIdx.x*16 + (tid>>6)*4 + (lane>>4);   // NN = 3125*16 exactly
    float adv = ad2[node];
    float4 acc; acc.x=acc.y=acc.z=acc.w=0.f;
    float ssum = 0.f;
    int base = offs[node], end = offs[node+1];
    for (int pos = base; pos < end; pos += 16){
        int m = end - pos; if (m > 16) m = 16;
        int src_l = 0; float p_l = 0.f;
        if (gl < m){
            src_l = csr[pos + gl];
            p_l = expf(lrelu(as2[src_l] + adv));   // one exp per edge, 16 in parallel per group
        }
        if (m == 16){
            #pragma unroll
            for (int j=0;j<16;j++){
                int srcj = __shfl(src_l, gb + j);
                float pj = __shfl(p_l, gb + j);
                ssum += pj;
                ushort4 hb = *(const ushort4*)(h2b + (size_t)srcj*HIDC + gl*4);
                acc.x = fmaf(pj, bf2f(hb.x), acc.x);
                acc.y = fmaf(pj, bf2f(hb.y), acc.y);
                acc.z = fmaf(pj, bf2f(hb.z), acc.z);
                acc.w = fmaf(pj, bf2f(hb.w), acc.w);
            }
        } else {
            for (int j=0;j<m;j++){
                int srcj = __shfl(src_l, gb + j);
                float pj = __shfl(p_l, gb + j);
                ssum += pj;
                ushort4 hb = *(const ushort4*)(h2b + (size_t)srcj*HIDC + gl*4);
                acc.x = fmaf(pj, bf2f(hb.x), acc.x);
                acc.y = fmaf(pj, bf2f(hb.y), acc.y);
                acc.z = fmaf(pj, bf2f(hb.z), acc.z);
                acc.w = fmaf(pj, bf2f(hb.w), acc.w);
            }
        }
    }
    {   // self loop (replicated across group's 16 lanes)
        float p = expf(lrelu(as2[node] + adv));
        ssum += p;
        ushort4 hb = *(const ushort4*)(h2b + (size_t)node*HIDC + gl*4);
        acc.x = fmaf(p, bf2f(hb.x), acc.x);
        acc.y = fmaf(p, bf2f(hb.y), acc.y);
        acc.z = fmaf(p, bf2f(hb.z), acc.z);
        acc.w = fmaf(p, bf2f(hb.w), acc.w);
    }
    float inv = 1.f/(ssum + 1e-16f);
    float4 bv = *(const float4*)(b2 + gl*4);
    float ox = eluf(fmaf(acc.x, inv, bv.x));
    float oy = eluf(fmaf(acc.y, inv, bv.y));
    float oz = eluf(fmaf(acc.z, inv, bv.z));
    float ow = eluf(fmaf(acc.w, inv, bv.w));
    int g = batch[node];
    float* pg = pool + g*HIDC + gl*4;
    atomicAdd(pg + 0, ox);
    atomicAdd(pg + 1, oy);
    atomicAdd(pg + 2, oz);
    atomicAdd(pg + 3, ow);
}

// ---------------- final MLP head, one block per graph ----------------
__global__ __launch_bounds__(128) void k_mlp(
    const float* __restrict__ pool, const int* __restrict__ gcnt,
    const float* __restrict__ l1w, const float* __restrict__ l1b,
    const float* __restrict__ l2w, const float* __restrict__ l2b,
    float* __restrict__ out)
{
    __shared__ float pl[64];
    __shared__ float wsum[2];
    int g = blockIdx.x, t = threadIdx.x;
    float inv = 1.f / fmaxf((float)gcnt[g], 1.f);
    if (t < 64) pl[t] = pool[g*64 + t] * inv;
    __syncthreads();
    float z = l1b[t];
    #pragma unroll 8
    for (int c=0;c<64;c++) z = fmaf(pl[c], l1w[c*128 + t], z);
    z = fmaxf(z, 0.f);
    float part = z * l2w[t];
    #pragma unroll
    for (int d=1; d<64; d<<=1) part += __shfl_xor(part, d);
    if ((t & 63) == 0) wsum[t>>6] = part;
    __syncthreads();
    if (t == 0) out[g] = wsum[0] + wsum[1] + l2b[0];
}

extern "C" void kernel_launch(void* const* d_in, const int* in_sizes, int n_in,
                              void* d_out, int out_size, void* d_ws, size_t ws_size,
                              hipStream_t stream) {
    const float* x    = (const float*)d_in[0];
    const int*   ei   = (const int*)d_in[1];
    const int*   batch= (const int*)d_in[2];
    const float* W1   = (const float*)d_in[3];
    const float* as1w = (const float*)d_in[4];
    const float* ad1w = (const float*)d_in[5];
    const float* b1   = (const float*)d_in[6];
    const float* W2   = (const float*)d_in[7];
    const float* as2w = (const float*)d_in[8];
    const float* ad2w = (const float*)d_in[9];
    const float* b2   = (const float*)d_in[10];
    const float* l1w  = (const float*)d_in[11];
    const float* l1b  = (const float*)d_in[12];
    const float* l2w  = (const float*)d_in[13];
    const float* l2b  = (const float*)d_in[14];
    float* out = (float*)d_out;

    char* ws = (char*)d_ws;
    size_t off = 0;
    auto alloc = [&](size_t bytes) -> void* {
        void* p = ws + off; off += (bytes + 255) & ~(size_t)255; return p;
    };
    unsigned short* h1b = (unsigned short*)alloc((size_t)NN*HC1*2);  // bf16 h1
    float* h1o  = (float*)alloc((size_t)NN*HC1*4);
    unsigned short* h2b = (unsigned short*)h1b;   // alias: h1 dead after k_agg1
    // CSR-build scratch aliases h1o (dead until k_agg1 writes it):
    unsigned* hist = (unsigned*)h1o;                       // 256*25000*4 = 25.6 MB
    unsigned short* bases = (unsigned short*)((char*)h1o + (size_t)NB*NW*4); // 25.6 MB
    float* as1  = (float*)alloc((size_t)NN*4*4);
    float* ad1  = (float*)alloc((size_t)NN*4*4);
    float* as2  = (float*)alloc((size_t)NN*4);
    float* ad2  = (float*)alloc((size_t)NN*4);
    int*   deg  = (int*)alloc((size_t)NN*4);
    int*   gcnt = (int*)alloc((size_t)NG*4);
    float* pool = (float*)alloc((size_t)NG*HIDC*4);
    int*   offs = (int*)alloc((size_t)(NN+16)*4);
    int*   bsum = (int*)alloc((size_t)256*4);
    int*   csr  = (int*)alloc((size_t)NE*4);
    (void)ws_size; (void)in_sizes; (void)n_in; (void)out_size;

    hipMemsetAsync(pool, 0, (size_t)NG*HIDC*4, stream);

    dim3 b256(256);
    int nb = (NN + 255)/256;
    k_hist   <<<dim3(NB), b256, 0, stream>>>(ei, hist);
    k_colscan<<<dim3(nb), b256, 0, stream>>>(hist, bases, deg);
    k_scanA  <<<dim3(nb), b256, 0, stream>>>(deg, offs, bsum);
    k_scanB  <<<dim3(1), b256, 0, stream>>>(bsum, nb);
    k_scanC  <<<dim3(nb), b256, 0, stream>>>(bsum, offs);
    k_place  <<<dim3(NB), b256, 0, stream>>>(ei, offs, bases, csr);
    k_gcnt   <<<dim3(1), dim3(64), 0, stream>>>(batch, gcnt);
    k_gemm1  <<<dim3((NN+63)/64, 2), b256, 0, stream>>>(x, W1, as1w, ad1w, h1b, as1, ad1);
    k_agg1   <<<dim3((NN+3)/4), b256, 0, stream>>>(h1b, as1, ad1, b1, offs, csr, h1o);
    k_gemm2  <<<dim3((NN+63)/64), b256, 0, stream>>>(h1o, W2, as2w, ad2w, h2b, as2, ad2);
    k_agg2   <<<dim3((NN+15)/16), b256, 0, stream>>>(h2b, as2, ad2, b2, offs, csr, batch, pool);
    k_mlp    <<<dim3(NG), dim3(128), 0, stream>>>(pool, gcnt, l1w, l1b, l2w, l2b, out);
}

// Round 12
// 376.177 us; speedup vs baseline: 1.3713x; 1.3713x over previous
//
#include <hip/hip_runtime.h>
#include <hip/hip_bf16.h>
#include <math.h>

#define NN 50000
#define NE 800000
#define NG 64
#define INC 128
#define HIDC 64
#define NH 4
#define HC1 256
#define NEG 0.2f
#define NB 256
#define CE (NE/NB)          // 3125 edges per hist block
#define NW (NN/2)           // 25000 packed u16-pair words

static __device__ __forceinline__ float lrelu(float x){ return x > 0.f ? x : NEG*x; }
static __device__ __forceinline__ float eluf(float x){ return x > 0.f ? x : expm1f(x); }
static __device__ __forceinline__ unsigned short f2bf(float x){
    unsigned u = __float_as_uint(x);
    unsigned r = u + 0x7fffu + ((u>>16)&1u);
    return (unsigned short)(r>>16);
}
static __device__ __forceinline__ float bf2f(unsigned short b){
    return __uint_as_float(((unsigned)b) << 16);
}

// ---------------- Phase A: per-block-chunk histogram (LDS, packed 2xu16) ----------------
__global__ __launch_bounds__(256) void k_hist(const int* __restrict__ ei, unsigned* __restrict__ hist)
{
    __shared__ unsigned h[NW];          // 100 KB
    int tid = threadIdx.x, b = blockIdx.x;
    for (int w = tid; w < NW; w += 256) h[w] = 0u;
    __syncthreads();
    const int* dsts = ei + NE + b*CE;
    for (int i = tid; i < CE; i += 256){
        int d = dsts[i];
        atomicAdd(&h[d>>1], 1u << (16*(d&1)));
    }
    __syncthreads();
    unsigned* out = hist + (size_t)b*NW;
    for (int w = tid; w < NW; w += 256) out[w] = h[w];
}

// ---------------- Phase B: column scan over blocks -> per-block u16 bases + node degree ----------------
__global__ __launch_bounds__(256) void k_colscan(const unsigned* __restrict__ hist,
                                                 unsigned short* __restrict__ bases,
                                                 int* __restrict__ deg)
{
    int n = blockIdx.x*256 + threadIdx.x;
    if (n >= NN) return;
    int w = n>>1, sh = 16*(n&1);
    unsigned run = 0;
    #pragma unroll 8
    for (int b = 0; b < NB; b++){
        unsigned c = (hist[(size_t)b*NW + w] >> sh) & 0xffffu;
        bases[(size_t)b*NN + n] = (unsigned short)run;
        run += c;
    }
    deg[n] = (int)run;
}

// ---------------- exclusive scan (3 kernels) ----------------
__global__ void k_scanA(const int* __restrict__ cnt, int* __restrict__ offs, int* __restrict__ bsum)
{
    __shared__ int s[256];
    int t = threadIdx.x;
    int i = blockIdx.x*256 + t;
    int v = (i < NN) ? cnt[i] : 0;
    s[t] = v; __syncthreads();
    #pragma unroll
    for (int d=1; d<256; d<<=1){
        int tv = (t>=d)? s[t-d] : 0; __syncthreads();
        s[t] += tv; __syncthreads();
    }
    if (i < NN) offs[i] = s[t] - v;
    if (t == 255) bsum[blockIdx.x] = s[255];
}

__global__ void k_scanB(int* __restrict__ bsum, int nb)
{
    __shared__ int s[256];
    int t = threadIdx.x;
    int v = (t < nb) ? bsum[t] : 0;
    s[t] = v; __syncthreads();
    #pragma unroll
    for (int d=1; d<256; d<<=1){
        int tv = (t>=d)? s[t-d] : 0; __syncthreads();
        s[t] += tv; __syncthreads();
    }
    if (t < nb) bsum[t] = s[t] - v;
}

__global__ void k_scanC(const int* __restrict__ bsum, int* __restrict__ offs)
{
    int t = threadIdx.x;
    int i = blockIdx.x*256 + t;
    if (i < NN) offs[i] += bsum[blockIdx.x];
    if (i == 0 && blockIdx.x == 0) offs[NN] = NE;
}

// ---------------- Phase C: place edges (LDS running rank, no global atomics) ----------------
__global__ __launch_bounds__(256) void k_place(const int* __restrict__ ei,
                                               const int* __restrict__ offs,
                                               const unsigned short* __restrict__ bases,
                                               int* __restrict__ csr)
{
    __shared__ unsigned h[NW];          // running ranks, packed
    int tid = threadIdx.x, b = blockIdx.x;
    for (int w = tid; w < NW; w += 256) h[w] = 0u;
    __syncthreads();
    const int* srcs = ei + b*CE;
    const int* dsts = ei + NE + b*CE;
    const unsigned short* myb = bases + (size_t)b*NN;
    for (int i = tid; i < CE; i += 256){
        int s = srcs[i], d = dsts[i];
        unsigned old = atomicAdd(&h[d>>1], 1u << (16*(d&1)));
        unsigned rank = (old >> (16*(d&1))) & 0xffffu;
        csr[(unsigned)offs[d] + (unsigned)myb[d] + rank] = s;
    }
}

// ---------------- graph sizes via binary search on sorted batch ----------------
__global__ void k_gcnt(const int* __restrict__ batch, int* __restrict__ gcnt)
{
    int g = threadIdx.x;
    if (g >= NG) return;
    int lo = 0, hi = NN;
    while (lo < hi){ int mid = (lo+hi)>>1; if (batch[mid] < g) lo = mid+1; else hi = mid; }
    int a = lo;
    lo = 0; hi = NN;
    while (lo < hi){ int mid = (lo+hi)>>1; if (batch[mid] < g+1) lo = mid+1; else hi = mid; }
    gcnt[g] = lo - a;
}

// ---------------- GEMM1: h1 = x@W1 (bf16 out), fused alpha_src/alpha_dst (fp32) ----------------
__global__ __launch_bounds__(256) void k_gemm1(
    const float* __restrict__ x, const float* __restrict__ W1,
    const float* __restrict__ aw_s, const float* __restrict__ aw_d,
    unsigned short* __restrict__ h1b, float* __restrict__ as1, float* __restrict__ ad1)
{
    __shared__ float Al[64][68];
    __shared__ float Bl[64][128];
    int tid = threadIdx.x;
    int r0 = blockIdx.x * 64;
    int c0 = blockIdx.y * 128;
    float acc[8][4];
    #pragma unroll
    for (int i=0;i<8;i++){
        #pragma unroll
        for (int j=0;j<4;j++) acc[i][j]=0.f;
    }

    for (int k0 = 0; k0 < INC; k0 += 64) {
        {   // stage A (64 rows x 64 k)
            int row = tid>>2, q = tid&3;
            int gr = r0 + row; if (gr >= NN) gr = NN-1;
            const float4* srcp = (const float4*)(x + (size_t)gr*INC + k0 + q*16);
            float4* dstp = (float4*)(&Al[row][q*16]);
            #pragma unroll
            for (int j=0;j<4;j++) dstp[j] = srcp[j];
        }
        {   // stage B (64 k x 128 cols)
            int kk = tid>>5, f = tid&31;
            #pragma unroll
            for (int p=0;p<8;p++){
                int k = kk + p*8;
                ((float4*)(&Bl[k][0]))[f] = ((const float4*)(W1 + (size_t)(k0+k)*HC1 + c0))[f];
            }
        }
        __syncthreads();
        int rg = tid>>5, cg = tid&31;
        #pragma unroll 4
        for (int k=0;k<64;k++){
            float4 b = ((const float4*)(&Bl[k][0]))[cg];
            #pragma unroll
            for (int i=0;i<8;i++){
                float a = Al[rg*8+i][k];
                acc[i][0] = fmaf(a, b.x, acc[i][0]);
                acc[i][1] = fmaf(a, b.y, acc[i][1]);
                acc[i][2] = fmaf(a, b.z, acc[i][2]);
                acc[i][3] = fmaf(a, b.w, acc[i][3]);
            }
        }
        __syncthreads();
    }
    int rg = tid>>5, cg = tid&31;
    int cbase = c0 + cg*4;
    int head = cbase >> 6;
    int cw = cbase & 63;
    float4 wsv = *(const float4*)(aw_s + head*HIDC + cw);
    float4 wdv = *(const float4*)(aw_d + head*HIDC + cw);
    #pragma unroll
    for (int i=0;i<8;i++){
        int gr = r0 + rg*8 + i;
        bool ok = gr < NN;
        float4 c4; c4.x=acc[i][0]; c4.y=acc[i][1]; c4.z=acc[i][2]; c4.w=acc[i][3];
        if (ok){
            ushort4 hb;
            hb.x = f2bf(c4.x); hb.y = f2bf(c4.y); hb.z = f2bf(c4.z); hb.w = f2bf(c4.w);
            *(ushort4*)(h1b + (size_t)gr*HC1 + cbase) = hb;
        }
        float ps = c4.x*wsv.x + c4.y*wsv.y + c4.z*wsv.z + c4.w*wsv.w;
        float pd = c4.x*wdv.x + c4.y*wdv.y + c4.z*wdv.z + c4.w*wdv.w;
        #pragma unroll
        for (int d=1; d<16; d<<=1){
            ps += __shfl_xor(ps, d);
            pd += __shfl_xor(pd, d);
        }
        if (((cg & 15) == 0) && ok){
            as1[gr*4 + head] = ps;
            ad1[gr*4 + head] = pd;
        }
    }
}

// ---------------- aggregation layer 1: hoisted edge weights, one wave per dst ----------------
__global__ __launch_bounds__(256) void k_agg1(
    const unsigned short* __restrict__ h1b, const float* __restrict__ as1, const float* __restrict__ ad1,
    const float* __restrict__ b1, const int* __restrict__ offs, const int* __restrict__ csr,
    float* __restrict__ h1o)
{
    int node = blockIdx.x*4 + (threadIdx.x>>6);
    if (node >= NN) return;
    int lane = threadIdx.x & 63;
    int hd = lane >> 4;
    float adv_l = ad1[node*4 + (lane&3)];   // head (lane&3) dst-logit, for hoisted p
    float4 acc; acc.x=acc.y=acc.z=acc.w=0.f;
    float ssum = 0.f;
    int base = offs[node], end = offs[node+1];
    for (int pos = base; pos < end; pos += 64){
        int nchunk = end - pos; if (nchunk > 64) nchunk = 64;
        int src_l = (lane < nchunk) ? csr[pos + lane] : 0;
        for (int sc = 0; sc*16 < nchunk; sc++){
            int srcv = __shfl(src_l, sc*16 + (lane>>2));
            float asv = as1[srcv*4 + (lane&3)];          // lane 4j+q: as of edge j, head q
            float p_l = expf(lrelu(asv + adv_l));        // hoisted: one exp per lane per 16 edges
            int m = nchunk - sc*16; if (m > 16) m = 16;
            if (m == 16){
                #pragma unroll
                for (int j=0;j<16;j++){
                    int srcj = __shfl(src_l, sc*16 + j);
                    float pj = __shfl(p_l, 4*j + hd);
                    ssum += pj;
                    ushort4 hb = *(const ushort4*)(h1b + (size_t)srcj*HC1 + lane*4);
                    acc.x = fmaf(pj, bf2f(hb.x), acc.x);
                    acc.y = fmaf(pj, bf2f(hb.y), acc.y);
                    acc.z = fmaf(pj, bf2f(hb.z), acc.z);
                    acc.w = fmaf(pj, bf2f(hb.w), acc.w);
                }
            } else {
                for (int j=0;j<m;j++){
                    int srcj = __shfl(src_l, sc*16 + j);
                    float pj = __shfl(p_l, 4*j + hd);
                    ssum += pj;
                    ushort4 hb = *(const ushort4*)(h1b + (size_t)srcj*HC1 + lane*4);
                    acc.x = fmaf(pj, bf2f(hb.x), acc.x);
                    acc.y = fmaf(pj, bf2f(hb.y), acc.y);
                    acc.z = fmaf(pj, bf2f(hb.z), acc.z);
                    acc.w = fmaf(pj, bf2f(hb.w), acc.w);
                }
            }
        }
    }
    {   // self loop (head hd)
        float p = expf(lrelu(as1[node*4 + hd] + ad1[node*4 + hd]));
        ssum += p;
        ushort4 hb = *(const ushort4*)(h1b + (size_t)node*HC1 + lane*4);
        acc.x = fmaf(p, bf2f(hb.x), acc.x);
        acc.y = fmaf(p, bf2f(hb.y), acc.y);
        acc.z = fmaf(p, bf2f(hb.z), acc.z);
        acc.w = fmaf(p, bf2f(hb.w), acc.w);
    }
    float inv = 1.f/(ssum + 1e-16f);
    float4 bv = ((const float4*)b1)[lane];
    float4 o;
    o.x = eluf(fmaf(acc.x, inv, bv.x));
    o.y = eluf(fmaf(acc.y, inv, bv.y));
    o.z = eluf(fmaf(acc.z, inv, bv.z));
    o.w = eluf(fmaf(acc.w, inv, bv.w));
    ((float4*)h1o)[(size_t)node*64 + lane] = o;
}

// ---------------- GEMM2: h2 = h1o@W2 (bf16 out), fused alpha (fp32) ----------------
__global__ __launch_bounds__(256) void k_gemm2(
    const float* __restrict__ h1o, const float* __restrict__ W2,
    const float* __restrict__ aw_s, const float* __restrict__ aw_d,
    unsigned short* __restrict__ h2b, float* __restrict__ as2, float* __restrict__ ad2)
{
    __shared__ float Al[64][68];
    __shared__ float Bl[64][64];
    int tid = threadIdx.x;
    int r0 = blockIdx.x * 64;
    float acc[4][4];
    #pragma unroll
    for (int i=0;i<4;i++){
        #pragma unroll
        for (int j=0;j<4;j++) acc[i][j]=0.f;
    }

    for (int k0 = 0; k0 < HC1; k0 += 64) {
        {   // stage A
            int row = tid>>2, q = tid&3;
            int gr = r0 + row; if (gr >= NN) gr = NN-1;
            const float4* srcp = (const float4*)(h1o + (size_t)gr*HC1 + k0 + q*16);
            float4* dstp = (float4*)(&Al[row][q*16]);
            #pragma unroll
            for (int j=0;j<4;j++) dstp[j] = srcp[j];
        }
        {   // stage B (64 k x 64 cols)
            int kk = tid>>4, f = tid&15;
            #pragma unroll
            for (int p=0;p<4;p++){
                int k = kk + p*16;
                ((float4*)(&Bl[k][0]))[f] = ((const float4*)(W2 + (size_t)(k0+k)*HIDC))[f];
            }
        }
        __syncthreads();
        int rg = tid>>4, cg = tid&15;
        #pragma unroll 4
        for (int k=0;k<64;k++){
            float4 b = ((const float4*)(&Bl[k][0]))[cg];
            #pragma unroll
            for (int i=0;i<4;i++){
                float a = Al[rg*4+i][k];
                acc[i][0] = fmaf(a, b.x, acc[i][0]);
                acc[i][1] = fmaf(a, b.y, acc[i][1]);
                acc[i][2] = fmaf(a, b.z, acc[i][2]);
                acc[i][3] = fmaf(a, b.w, acc[i][3]);
            }
        }
        __syncthreads();
    }
    int rg = tid>>4, cg = tid&15;
    float4 wsv = ((const float4*)aw_s)[cg];
    float4 wdv = ((const float4*)aw_d)[cg];
    #pragma unroll
    for (int i=0;i<4;i++){
        int gr = r0 + rg*4 + i;
        bool ok = gr < NN;
        float4 c4; c4.x=acc[i][0]; c4.y=acc[i][1]; c4.z=acc[i][2]; c4.w=acc[i][3];
        if (ok){
            ushort4 hb;
            hb.x = f2bf(c4.x); hb.y = f2bf(c4.y); hb.z = f2bf(c4.z); hb.w = f2bf(c4.w);
            *(ushort4*)(h2b + (size_t)gr*HIDC + cg*4) = hb;
        }
        float ps = c4.x*wsv.x + c4.y*wsv.y + c4.z*wsv.z + c4.w*wsv.w;
        float pd = c4.x*wdv.x + c4.y*wdv.y + c4.z*wdv.z + c4.w*wdv.w;
        #pragma unroll
        for (int d=1; d<16; d<<=1){
            ps += __shfl_xor(ps, d);
            pd += __shfl_xor(pd, d);
        }
        if (cg == 0 && ok){
            as2[gr] = ps;
            ad2[gr] = pd;
        }
    }
}

// ---------------- aggregation layer 2: r8 structure + block-level LDS pool combine ----------------
// One node per 64-lane wave (wave-uniform shfl -> readlane + scalar-base loads).
// 4 waves/block stage results in LDS; wave 0 sums and issues ONE atomic set per block
// (4x fewer global atomics; consecutive nodes share a graph except at ~63 boundaries).
__global__ __launch_bounds__(256) void k_agg2(
    const unsigned short* __restrict__ h2b, const float* __restrict__ as2, const float* __restrict__ ad2,
    const float* __restrict__ b2, const int* __restrict__ offs, const int* __restrict__ csr,
    const int* __restrict__ batch, float* __restrict__ pool)
{
    __shared__ float pacc[4][64];
    __shared__ int gs[4];
    int tid = threadIdx.x;
    int wid = tid >> 6;
    int lane = tid & 63;
    int node = blockIdx.x*4 + wid;        // NN % 4 == 0: always valid
    float adv = ad2[node];
    float accv = 0.f, ssum = 0.f;
    int base = offs[node], end = offs[node+1];
    for (int pos = base; pos < end; pos += 64){
        int nchunk = end - pos; if (nchunk > 64) nchunk = 64;
        int src_l = 0; float p_l = 0.f;
        if (lane < nchunk){
            src_l = csr[pos + lane];
            p_l = expf(lrelu(as2[src_l] + adv));   // hoisted: one exp per edge, all 64 in parallel
        }
        for (int sc = 0; sc*16 < nchunk; sc++){
            int m = nchunk - sc*16; if (m > 16) m = 16;
            if (m == 16){
                #pragma unroll
                for (int j=0;j<16;j++){
                    int jj = sc*16 + j;
                    int srcj = __shfl(src_l, jj);
                    float pj = __shfl(p_l, jj);
                    ssum += pj;
                    accv = fmaf(pj, bf2f(h2b[(size_t)srcj*HIDC + lane]), accv);
                }
            } else {
                for (int j=0;j<m;j++){
                    int jj = sc*16 + j;
                    int srcj = __shfl(src_l, jj);
                    float pj = __shfl(p_l, jj);
                    ssum += pj;
                    accv = fmaf(pj, bf2f(h2b[(size_t)srcj*HIDC + lane]), accv);
                }
            }
        }
    }
    {   // self loop
        float p = expf(lrelu(as2[node] + adv));
        ssum += p;
        accv = fmaf(p, bf2f(h2b[(size_t)node*HIDC + lane]), accv);
    }
    float o = eluf(accv/(ssum + 1e-16f) + b2[lane]);
    int g = batch[node];
    pacc[wid][lane] = o;
    if (lane == 0) gs[wid] = g;
    __syncthreads();
    if (gs[0] == gs[1] && gs[1] == gs[2] && gs[2] == gs[3]){
        if (wid == 0){
            float s = (pacc[0][lane] + pacc[1][lane]) + (pacc[2][lane] + pacc[3][lane]);
            atomicAdd(&pool[g*HIDC + lane], s);
        }
    } else {
        atomicAdd(&pool[g*HIDC + lane], o);   // rare graph-boundary block
    }
}

// ---------------- final MLP head, one block per graph ----------------
__global__ __launch_bounds__(128) void k_mlp(
    const float* __restrict__ pool, const int* __restrict__ gcnt,
    const float* __restrict__ l1w, const float* __restrict__ l1b,
    const float* __restrict__ l2w, const float* __restrict__ l2b,
    float* __restrict__ out)
{
    __shared__ float pl[64];
    __shared__ float wsum[2];
    int g = blockIdx.x, t = threadIdx.x;
    float inv = 1.f / fmaxf((float)gcnt[g], 1.f);
    if (t < 64) pl[t] = pool[g*64 + t] * inv;
    __syncthreads();
    float z = l1b[t];
    #pragma unroll 8
    for (int c=0;c<64;c++) z = fmaf(pl[c], l1w[c*128 + t], z);
    z = fmaxf(z, 0.f);
    float part = z * l2w[t];
    #pragma unroll
    for (int d=1; d<64; d<<=1) part += __shfl_xor(part, d);
    if ((t & 63) == 0) wsum[t>>6] = part;
    __syncthreads();
    if (t == 0) out[g] = wsum[0] + wsum[1] + l2b[0];
}

extern "C" void kernel_launch(void* const* d_in, const int* in_sizes, int n_in,
                              void* d_out, int out_size, void* d_ws, size_t ws_size,
                              hipStream_t stream) {
    const float* x    = (const float*)d_in[0];
    const int*   ei   = (const int*)d_in[1];
    const int*   batch= (const int*)d_in[2];
    const float* W1   = (const float*)d_in[3];
    const float* as1w = (const float*)d_in[4];
    const float* ad1w = (const float*)d_in[5];
    const float* b1   = (const float*)d_in[6];
    const float* W2   = (const float*)d_in[7];
    const float* as2w = (const float*)d_in[8];
    const float* ad2w = (const float*)d_in[9];
    const float* b2   = (const float*)d_in[10];
    const float* l1w  = (const float*)d_in[11];
    const float* l1b  = (const float*)d_in[12];
    const float* l2w  = (const float*)d_in[13];
    const float* l2b  = (const float*)d_in[14];
    float* out = (float*)d_out;

    char* ws = (char*)d_ws;
    size_t off = 0;
    auto alloc = [&](size_t bytes) -> void* {
        void* p = ws + off; off += (bytes + 255) & ~(size_t)255; return p;
    };
    unsigned short* h1b = (unsigned short*)alloc((size_t)NN*HC1*2);  // bf16 h1
    float* h1o  = (float*)alloc((size_t)NN*HC1*4);
    unsigned short* h2b = (unsigned short*)h1b;   // alias: h1 dead after k_agg1
    // CSR-build scratch aliases h1o (dead until k_agg1 writes it):
    unsigned* hist = (unsigned*)h1o;                       // 256*25000*4 = 25.6 MB
    unsigned short* bases = (unsigned short*)((char*)h1o + (size_t)NB*NW*4); // 25.6 MB
    float* as1  = (float*)alloc((size_t)NN*4*4);
    float* ad1  = (float*)alloc((size_t)NN*4*4);
    float* as2  = (float*)alloc((size_t)NN*4);
    float* ad2  = (float*)alloc((size_t)NN*4);
    int*   deg  = (int*)alloc((size_t)NN*4);
    int*   gcnt = (int*)alloc((size_t)NG*4);
    float* pool = (float*)alloc((size_t)NG*HIDC*4);
    int*   offs = (int*)alloc((size_t)(NN+16)*4);
    int*   bsum = (int*)alloc((size_t)256*4);
    int*   csr  = (int*)alloc((size_t)NE*4);
    (void)ws_size; (void)in_sizes; (void)n_in; (void)out_size;

    hipMemsetAsync(pool, 0, (size_t)NG*HIDC*4, stream);

    dim3 b256(256);
    int nb = (NN + 255)/256;
    k_hist   <<<dim3(NB), b256, 0, stream>>>(ei, hist);
    k_colscan<<<dim3(nb), b256, 0, stream>>>(hist, bases, deg);
    k_scanA  <<<dim3(nb), b256, 0, stream>>>(deg, offs, bsum);
    k_scanB  <<<dim3(1), b256, 0, stream>>>(bsum, nb);
    k_scanC  <<<dim3(nb), b256, 0, stream>>>(bsum, offs);
    k_place  <<<dim3(NB), b256, 0, stream>>>(ei, offs, bases, csr);
    k_gcnt   <<<dim3(1), dim3(64), 0, stream>>>(batch, gcnt);
    k_gemm1  <<<dim3((NN+63)/64, 2), b256, 0, stream>>>(x, W1, as1w, ad1w, h1b, as1, ad1);
    k_agg1   <<<dim3((NN+3)/4), b256, 0, stream>>>(h1b, as1, ad1, b1, offs, csr, h1o);
    k_gemm2  <<<dim3((NN+63)/64), b256, 0, stream>>>(h1o, W2, as2w, ad2w, h2b, as2, ad2);
    k_agg2   <<<dim3((NN+3)/4), b256, 0, stream>>>(h2b, as2, ad2, b2, offs, csr, batch, pool);
    k_mlp    <<<dim3(NG), dim3(128), 0, stream>>>(pool, gcnt, l1w, l1b, l2w, l2b, out);
}

// Round 13
// 365.773 us; speedup vs baseline: 1.4103x; 1.0284x over previous
//
#include <hip/hip_runtime.h>
#include <hip/hip_bf16.h>
#include <math.h>

#define NN 50000
#define NE 800000
#define NG 64
#define INC 128
#define HIDC 64
#define NH 4
#define HC1 256
#define NEG 0.2f
#define NB 256
#define CE (NE/NB)          // 3125 edges per hist block
#define NW (NN/2)           // 25000 packed u16-pair words

static __device__ __forceinline__ float lrelu(float x){ return x > 0.f ? x : NEG*x; }
static __device__ __forceinline__ float eluf(float x){ return x > 0.f ? x : expm1f(x); }
static __device__ __forceinline__ unsigned short f2bf(float x){
    unsigned u = __float_as_uint(x);
    unsigned r = u + 0x7fffu + ((u>>16)&1u);
    return (unsigned short)(r>>16);
}
static __device__ __forceinline__ float bf2f(unsigned short b){
    return __uint_as_float(((unsigned)b) << 16);
}

// ---------------- Phase A: per-block-chunk histogram (LDS, packed 2xu16) ----------------
__global__ __launch_bounds__(256) void k_hist(const int* __restrict__ ei, unsigned* __restrict__ hist)
{
    __shared__ unsigned h[NW];          // 100 KB
    int tid = threadIdx.x, b = blockIdx.x;
    for (int w = tid; w < NW; w += 256) h[w] = 0u;
    __syncthreads();
    const int* dsts = ei + NE + b*CE;
    for (int i = tid; i < CE; i += 256){
        int d = dsts[i];
        atomicAdd(&h[d>>1], 1u << (16*(d&1)));
    }
    __syncthreads();
    unsigned* out = hist + (size_t)b*NW;
    for (int w = tid; w < NW; w += 256) out[w] = h[w];
}

// ---------------- Phase B: column scan over blocks -> per-block u16 bases + node degree ----------------
__global__ __launch_bounds__(256) void k_colscan(const unsigned* __restrict__ hist,
                                                 unsigned short* __restrict__ bases,
                                                 int* __restrict__ deg)
{
    int n = blockIdx.x*256 + threadIdx.x;
    if (n >= NN) return;
    int w = n>>1, sh = 16*(n&1);
    unsigned run = 0;
    #pragma unroll 8
    for (int b = 0; b < NB; b++){
        unsigned c = (hist[(size_t)b*NW + w] >> sh) & 0xffffu;
        bases[(size_t)b*NN + n] = (unsigned short)run;
        run += c;
    }
    deg[n] = (int)run;
}

// ---------------- exclusive scan (3 kernels) ----------------
__global__ void k_scanA(const int* __restrict__ cnt, int* __restrict__ offs, int* __restrict__ bsum)
{
    __shared__ int s[256];
    int t = threadIdx.x;
    int i = blockIdx.x*256 + t;
    int v = (i < NN) ? cnt[i] : 0;
    s[t] = v; __syncthreads();
    #pragma unroll
    for (int d=1; d<256; d<<=1){
        int tv = (t>=d)? s[t-d] : 0; __syncthreads();
        s[t] += tv; __syncthreads();
    }
    if (i < NN) offs[i] = s[t] - v;
    if (t == 255) bsum[blockIdx.x] = s[255];
}

__global__ void k_scanB(int* __restrict__ bsum, int nb)
{
    __shared__ int s[256];
    int t = threadIdx.x;
    int v = (t < nb) ? bsum[t] : 0;
    s[t] = v; __syncthreads();
    #pragma unroll
    for (int d=1; d<256; d<<=1){
        int tv = (t>=d)? s[t-d] : 0; __syncthreads();
        s[t] += tv; __syncthreads();
    }
    if (t < nb) bsum[t] = s[t] - v;
}

__global__ void k_scanC(const int* __restrict__ bsum, int* __restrict__ offs)
{
    int t = threadIdx.x;
    int i = blockIdx.x*256 + t;
    if (i < NN) offs[i] += bsum[blockIdx.x];
    if (i == 0 && blockIdx.x == 0) offs[NN] = NE;
}

// ---------------- Phase C: place edges (LDS running rank, no global atomics) ----------------
__global__ __launch_bounds__(256) void k_place(const int* __restrict__ ei,
                                               const int* __restrict__ offs,
                                               const unsigned short* __restrict__ bases,
                                               int* __restrict__ csr)
{
    __shared__ unsigned h[NW];          // running ranks, packed
    int tid = threadIdx.x, b = blockIdx.x;
    for (int w = tid; w < NW; w += 256) h[w] = 0u;
    __syncthreads();
    const int* srcs = ei + b*CE;
    const int* dsts = ei + NE + b*CE;
    const unsigned short* myb = bases + (size_t)b*NN;
    for (int i = tid; i < CE; i += 256){
        int s = srcs[i], d = dsts[i];
        unsigned old = atomicAdd(&h[d>>1], 1u << (16*(d&1)));
        unsigned rank = (old >> (16*(d&1))) & 0xffffu;
        csr[(unsigned)offs[d] + (unsigned)myb[d] + rank] = s;
    }
}

// ---------------- GEMM1: h1 = x@W1 (bf16 out), fused alpha_src/alpha_dst (fp32) ----------------
__global__ __launch_bounds__(256) void k_gemm1(
    const float* __restrict__ x, const float* __restrict__ W1,
    const float* __restrict__ aw_s, const float* __restrict__ aw_d,
    unsigned short* __restrict__ h1b, float* __restrict__ as1, float* __restrict__ ad1)
{
    __shared__ float Al[64][68];
    __shared__ float Bl[64][128];
    int tid = threadIdx.x;
    int r0 = blockIdx.x * 64;
    int c0 = blockIdx.y * 128;
    float acc[8][4];
    #pragma unroll
    for (int i=0;i<8;i++){
        #pragma unroll
        for (int j=0;j<4;j++) acc[i][j]=0.f;
    }

    for (int k0 = 0; k0 < INC; k0 += 64) {
        {   // stage A (64 rows x 64 k)
            int row = tid>>2, q = tid&3;
            int gr = r0 + row; if (gr >= NN) gr = NN-1;
            const float4* srcp = (const float4*)(x + (size_t)gr*INC + k0 + q*16);
            float4* dstp = (float4*)(&Al[row][q*16]);
            #pragma unroll
            for (int j=0;j<4;j++) dstp[j] = srcp[j];
        }
        {   // stage B (64 k x 128 cols)
            int kk = tid>>5, f = tid&31;
            #pragma unroll
            for (int p=0;p<8;p++){
                int k = kk + p*8;
                ((float4*)(&Bl[k][0]))[f] = ((const float4*)(W1 + (size_t)(k0+k)*HC1 + c0))[f];
            }
        }
        __syncthreads();
        int rg = tid>>5, cg = tid&31;
        #pragma unroll 4
        for (int k=0;k<64;k++){
            float4 b = ((const float4*)(&Bl[k][0]))[cg];
            #pragma unroll
            for (int i=0;i<8;i++){
                float a = Al[rg*8+i][k];
                acc[i][0] = fmaf(a, b.x, acc[i][0]);
                acc[i][1] = fmaf(a, b.y, acc[i][1]);
                acc[i][2] = fmaf(a, b.z, acc[i][2]);
                acc[i][3] = fmaf(a, b.w, acc[i][3]);
            }
        }
        __syncthreads();
    }
    int rg = tid>>5, cg = tid&31;
    int cbase = c0 + cg*4;
    int head = cbase >> 6;
    int cw = cbase & 63;
    float4 wsv = *(const float4*)(aw_s + head*HIDC + cw);
    float4 wdv = *(const float4*)(aw_d + head*HIDC + cw);
    #pragma unroll
    for (int i=0;i<8;i++){
        int gr = r0 + rg*8 + i;
        bool ok = gr < NN;
        float4 c4; c4.x=acc[i][0]; c4.y=acc[i][1]; c4.z=acc[i][2]; c4.w=acc[i][3];
        if (ok){
            ushort4 hb;
            hb.x = f2bf(c4.x); hb.y = f2bf(c4.y); hb.z = f2bf(c4.z); hb.w = f2bf(c4.w);
            *(ushort4*)(h1b + (size_t)gr*HC1 + cbase) = hb;
        }
        float ps = c4.x*wsv.x + c4.y*wsv.y + c4.z*wsv.z + c4.w*wsv.w;
        float pd = c4.x*wdv.x + c4.y*wdv.y + c4.z*wdv.z + c4.w*wdv.w;
        #pragma unroll
        for (int d=1; d<16; d<<=1){
            ps += __shfl_xor(ps, d);
            pd += __shfl_xor(pd, d);
        }
        if (((cg & 15) == 0) && ok){
            as1[gr*4 + head] = ps;
            ad1[gr*4 + head] = pd;
        }
    }
}

// ---------------- aggregation layer 1: hoisted weights + byte-offsets, end-reduced ssum ----------------
__global__ __launch_bounds__(256) void k_agg1(
    const unsigned short* __restrict__ h1b, const float* __restrict__ as1, const float* __restrict__ ad1,
    const float* __restrict__ b1, const int* __restrict__ offs, const int* __restrict__ csr,
    float* __restrict__ h1o)
{
    int node = blockIdx.x*4 + (threadIdx.x>>6);
    if (node >= NN) return;
    int lane = threadIdx.x & 63;
    int hd = lane >> 4;
    float adv_l = ad1[node*4 + (lane&3)];   // head (lane&3) dst-logit, for hoisted p
    const char* hp = (const char*)h1b;
    int lb = lane*8;                        // this lane's byte offset within a row
    float4 acc; acc.x=acc.y=acc.z=acc.w=0.f;
    float psum_l = 0.f;                     // per-lane partial: p(edge lane>>2 of subchunk, head lane&3)
    int base = offs[node], end = offs[node+1];
    for (int pos = base; pos < end; pos += 64){
        int nchunk = end - pos; if (nchunk > 64) nchunk = 64;
        int boff_l = ((lane < nchunk) ? csr[pos + lane] : 0) << 9;  // src*512B
        for (int sc = 0; sc*16 < nchunk; sc++){
            int srcv_off = __shfl(boff_l, sc*16 + (lane>>2));
            float p_l = 0.f;
            if (sc*16 + (lane>>2) < nchunk){
                float asv = as1[(srcv_off >> 7) + (lane&3)];  // src*4 + head
                p_l = expf(lrelu(asv + adv_l));
            }
            psum_l += p_l;
            int m = nchunk - sc*16; if (m > 16) m = 16;
            if (m == 16){
                #pragma unroll
                for (int j=0;j<16;j++){
                    int so = __shfl(boff_l, sc*16 + j);
                    float pj = __shfl(p_l, 4*j + hd);
                    ushort4 hb = *(const ushort4*)(hp + so + lb);
                    acc.x = fmaf(pj, bf2f(hb.x), acc.x);
                    acc.y = fmaf(pj, bf2f(hb.y), acc.y);
                    acc.z = fmaf(pj, bf2f(hb.z), acc.z);
                    acc.w = fmaf(pj, bf2f(hb.w), acc.w);
                }
            } else {
                for (int j=0;j<m;j++){
                    int so = __shfl(boff_l, sc*16 + j);
                    float pj = __shfl(p_l, 4*j + hd);
                    ushort4 hb = *(const ushort4*)(hp + so + lb);
                    acc.x = fmaf(pj, bf2f(hb.x), acc.x);
                    acc.y = fmaf(pj, bf2f(hb.y), acc.y);
                    acc.z = fmaf(pj, bf2f(hb.z), acc.z);
                    acc.w = fmaf(pj, bf2f(hb.w), acc.w);
                }
            }
        }
    }
    // cross-lane ssum: sum psum_l over lanes with same (lane&3) -> S[q]; fetch S[hd]
    float s = psum_l;
    s += __shfl_xor(s, 4); s += __shfl_xor(s, 8);
    s += __shfl_xor(s, 16); s += __shfl_xor(s, 32);
    float ssum = __shfl(s, hd);             // lane "hd" (0..3) has q == hd
    {   // self loop (head hd)
        float p = expf(lrelu(as1[node*4 + hd] + ad1[node*4 + hd]));
        ssum += p;
        ushort4 hb = *(const ushort4*)(hp + (node << 9) + lb);
        acc.x = fmaf(p, bf2f(hb.x), acc.x);
        acc.y = fmaf(p, bf2f(hb.y), acc.y);
        acc.z = fmaf(p, bf2f(hb.z), acc.z);
        acc.w = fmaf(p, bf2f(hb.w), acc.w);
    }
    float inv = 1.f/(ssum + 1e-16f);
    float4 bv = ((const float4*)b1)[lane];
    float4 o;
    o.x = eluf(fmaf(acc.x, inv, bv.x));
    o.y = eluf(fmaf(acc.y, inv, bv.y));
    o.z = eluf(fmaf(acc.z, inv, bv.z));
    o.w = eluf(fmaf(acc.w, inv, bv.w));
    ((float4*)h1o)[(size_t)node*64 + lane] = o;
}

// ---------------- GEMM2: h2 = h1o@W2 (bf16 out), fused alpha (fp32) ----------------
__global__ __launch_bounds__(256) void k_gemm2(
    const float* __restrict__ h1o, const float* __restrict__ W2,
    const float* __restrict__ aw_s, const float* __restrict__ aw_d,
    unsigned short* __restrict__ h2b, float* __restrict__ as2, float* __restrict__ ad2)
{
    __shared__ float Al[64][68];
    __shared__ float Bl[64][64];
    int tid = threadIdx.x;
    int r0 = blockIdx.x * 64;
    float acc[4][4];
    #pragma unroll
    for (int i=0;i<4;i++){
        #pragma unroll
        for (int j=0;j<4;j++) acc[i][j]=0.f;
    }

    for (int k0 = 0; k0 < HC1; k0 += 64) {
        {   // stage A
            int row = tid>>2, q = tid&3;
            int gr = r0 + row; if (gr >= NN) gr = NN-1;
            const float4* srcp = (const float4*)(h1o + (size_t)gr*HC1 + k0 + q*16);
            float4* dstp = (float4*)(&Al[row][q*16]);
            #pragma unroll
            for (int j=0;j<4;j++) dstp[j] = srcp[j];
        }
        {   // stage B (64 k x 64 cols)
            int kk = tid>>4, f = tid&15;
            #pragma unroll
            for (int p=0;p<4;p++){
                int k = kk + p*16;
                ((float4*)(&Bl[k][0]))[f] = ((const float4*)(W2 + (size_t)(k0+k)*HIDC))[f];
            }
        }
        __syncthreads();
        int rg = tid>>4, cg = tid&15;
        #pragma unroll 4
        for (int k=0;k<64;k++){
            float4 b = ((const float4*)(&Bl[k][0]))[cg];
            #pragma unroll
            for (int i=0;i<4;i++){
                float a = Al[rg*4+i][k];
                acc[i][0] = fmaf(a, b.x, acc[i][0]);
                acc[i][1] = fmaf(a, b.y, acc[i][1]);
                acc[i][2] = fmaf(a, b.z, acc[i][2]);
                acc[i][3] = fmaf(a, b.w, acc[i][3]);
            }
        }
        __syncthreads();
    }
    int rg = tid>>4, cg = tid&15;
    float4 wsv = ((const float4*)aw_s)[cg];
    float4 wdv = ((const float4*)aw_d)[cg];
    #pragma unroll
    for (int i=0;i<4;i++){
        int gr = r0 + rg*4 + i;
        bool ok = gr < NN;
        float4 c4; c4.x=acc[i][0]; c4.y=acc[i][1]; c4.z=acc[i][2]; c4.w=acc[i][3];
        if (ok){
            ushort4 hb;
            hb.x = f2bf(c4.x); hb.y = f2bf(c4.y); hb.z = f2bf(c4.z); hb.w = f2bf(c4.w);
            *(ushort4*)(h2b + (size_t)gr*HIDC + cg*4) = hb;
        }
        float ps = c4.x*wsv.x + c4.y*wsv.y + c4.z*wsv.z + c4.w*wsv.w;
        float pd = c4.x*wdv.x + c4.y*wdv.y + c4.z*wdv.z + c4.w*wdv.w;
        #pragma unroll
        for (int d=1; d<16; d<<=1){
            ps += __shfl_xor(ps, d);
            pd += __shfl_xor(pd, d);
        }
        if (cg == 0 && ok){
            as2[gr] = ps;
            ad2[gr] = pd;
        }
    }
}

// ---------------- aggregation layer 2: r8 structure + trims + block LDS pool combine ----------------
__global__ __launch_bounds__(256) void k_agg2(
    const unsigned short* __restrict__ h2b, const float* __restrict__ as2, const float* __restrict__ ad2,
    const float* __restrict__ b2, const int* __restrict__ offs, const int* __restrict__ csr,
    const int* __restrict__ batch, float* __restrict__ pool)
{
    __shared__ float pacc[4][64];
    __shared__ int gs[4];
    int tid = threadIdx.x;
    int wid = tid >> 6;
    int lane = tid & 63;
    int node = blockIdx.x*4 + wid;        // NN % 4 == 0: always valid
    float adv = ad2[node];
    const char* hp = (const char*)h2b;
    int lb = lane*2;
    float accv = 0.f, psum_l = 0.f;
    int base = offs[node], end = offs[node+1];
    for (int pos = base; pos < end; pos += 64){
        int nchunk = end - pos; if (nchunk > 64) nchunk = 64;
        int boff_l = 0; float p_l = 0.f;
        if (lane < nchunk){
            int src_l = csr[pos + lane];
            boff_l = src_l << 7;                    // src*128B
            p_l = expf(lrelu(as2[src_l] + adv));    // hoisted: one exp per edge
        }
        psum_l += p_l;
        for (int sc = 0; sc*16 < nchunk; sc++){
            int m = nchunk - sc*16; if (m > 16) m = 16;
            if (m == 16){
                #pragma unroll
                for (int j=0;j<16;j++){
                    int jj = sc*16 + j;
                    int so = __shfl(boff_l, jj);
                    float pj = __shfl(p_l, jj);
                    accv = fmaf(pj, bf2f(*(const unsigned short*)(hp + so + lb)), accv);
                }
            } else {
                for (int j=0;j<m;j++){
                    int jj = sc*16 + j;
                    int so = __shfl(boff_l, jj);
                    float pj = __shfl(p_l, jj);
                    accv = fmaf(pj, bf2f(*(const unsigned short*)(hp + so + lb)), accv);
                }
            }
        }
    }
    // full-wave reduce of psum_l -> ssum (all lanes)
    float ssum = psum_l;
    ssum += __shfl_xor(ssum, 1); ssum += __shfl_xor(ssum, 2);
    ssum += __shfl_xor(ssum, 4); ssum += __shfl_xor(ssum, 8);
    ssum += __shfl_xor(ssum, 16); ssum += __shfl_xor(ssum, 32);
    {   // self loop
        float p = expf(lrelu(as2[node] + adv));
        ssum += p;
        accv = fmaf(p, bf2f(*(const unsigned short*)(hp + (node << 7) + lb)), accv);
    }
    float o = eluf(accv/(ssum + 1e-16f) + b2[lane]);
    int g = batch[node];
    pacc[wid][lane] = o;
    if (lane == 0) gs[wid] = g;
    __syncthreads();
    if (gs[0] == gs[1] && gs[1] == gs[2] && gs[2] == gs[3]){
        if (wid == 0){
            float s = (pacc[0][lane] + pacc[1][lane]) + (pacc[2][lane] + pacc[3][lane]);
            atomicAdd(&pool[g*HIDC + lane], s);
        }
    } else {
        atomicAdd(&pool[g*HIDC + lane], o);   // rare graph-boundary block
    }
}

// ---------------- final MLP head (gcnt folded in), one block per graph ----------------
__global__ __launch_bounds__(128) void k_mlp(
    const float* __restrict__ pool, const int* __restrict__ batch,
    const float* __restrict__ l1w, const float* __restrict__ l1b,
    const float* __restrict__ l2w, const float* __restrict__ l2b,
    float* __restrict__ out)
{
    __shared__ float pl[64];
    __shared__ float wsum[2];
    int g = blockIdx.x, t = threadIdx.x;
    // per-graph node count via binary search on sorted batch (uniform across threads)
    int lo = 0, hi = NN;
    while (lo < hi){ int mid = (lo+hi)>>1; if (batch[mid] < g) lo = mid+1; else hi = mid; }
    int a = lo;
    lo = 0; hi = NN;
    while (lo < hi){ int mid = (lo+hi)>>1; if (batch[mid] < g+1) lo = mid+1; else hi = mid; }
    float inv = 1.f / fmaxf((float)(lo - a), 1.f);
    if (t < 64) pl[t] = pool[g*64 + t] * inv;
    __syncthreads();
    float z = l1b[t];
    #pragma unroll 8
    for (int c=0;c<64;c++) z = fmaf(pl[c], l1w[c*128 + t], z);
    z = fmaxf(z, 0.f);
    float part = z * l2w[t];
    #pragma unroll
    for (int d=1; d<64; d<<=1) part += __shfl_xor(part, d);
    if ((t & 63) == 0) wsum[t>>6] = part;
    __syncthreads();
    if (t == 0) out[g] = wsum[0] + wsum[1] + l2b[0];
}

extern "C" void kernel_launch(void* const* d_in, const int* in_sizes, int n_in,
                              void* d_out, int out_size, void* d_ws, size_t ws_size,
                              hipStream_t stream) {
    const float* x    = (const float*)d_in[0];
    const int*   ei   = (const int*)d_in[1];
    const int*   batch= (const int*)d_in[2];
    const float* W1   = (const float*)d_in[3];
    const float* as1w = (const float*)d_in[4];
    const float* ad1w = (const float*)d_in[5];
    const float* b1   = (const float*)d_in[6];
    const float* W2   = (const float*)d_in[7];
    const float* as2w = (const float*)d_in[8];
    const float* ad2w = (const float*)d_in[9];
    const float* b2   = (const float*)d_in[10];
    const float* l1w  = (const float*)d_in[11];
    const float* l1b  = (const float*)d_in[12];
    const float* l2w  = (const float*)d_in[13];
    const float* l2b  = (const float*)d_in[14];
    float* out = (float*)d_out;

    char* ws = (char*)d_ws;
    size_t off = 0;
    auto alloc = [&](size_t bytes) -> void* {
        void* p = ws + off; off += (bytes + 255) & ~(size_t)255; return p;
    };
    unsigned short* h1b = (unsigned short*)alloc((size_t)NN*HC1*2);  // bf16 h1
    float* h1o  = (float*)alloc((size_t)NN*HC1*4);
    unsigned short* h2b = (unsigned short*)h1b;   // alias: h1 dead after k_agg1
    // CSR-build scratch aliases h1o (dead until k_agg1 writes it):
    unsigned* hist = (unsigned*)h1o;                       // 256*25000*4 = 25.6 MB
    unsigned short* bases = (unsigned short*)((char*)h1o + (size_t)NB*NW*4); // 25.6 MB
    float* as1  = (float*)alloc((size_t)NN*4*4);
    float* ad1  = (float*)alloc((size_t)NN*4*4);
    float* as2  = (float*)alloc((size_t)NN*4);
    float* ad2  = (float*)alloc((size_t)NN*4);
    int*   deg  = (int*)alloc((size_t)NN*4);
    float* pool = (float*)alloc((size_t)NG*HIDC*4);
    int*   offs = (int*)alloc((size_t)(NN+16)*4);
    int*   bsum = (int*)alloc((size_t)256*4);
    int*   csr  = (int*)alloc((size_t)NE*4);
    (void)ws_size; (void)in_sizes; (void)n_in; (void)out_size;

    hipMemsetAsync(pool, 0, (size_t)NG*HIDC*4, stream);

    dim3 b256(256);
    int nb = (NN + 255)/256;
    k_hist   <<<dim3(NB), b256, 0, stream>>>(ei, hist);
    k_colscan<<<dim3(nb), b256, 0, stream>>>(hist, bases, deg);
    k_scanA  <<<dim3(nb), b256, 0, stream>>>(deg, offs, bsum);
    k_scanB  <<<dim3(1), b256, 0, stream>>>(bsum, nb);
    k_scanC  <<<dim3(nb), b256, 0, stream>>>(bsum, offs);
    k_place  <<<dim3(NB), b256, 0, stream>>>(ei, offs, bases, csr);
    k_gemm1  <<<dim3((NN+63)/64, 2), b256, 0, stream>>>(x, W1, as1w, ad1w, h1b, as1, ad1);
    k_agg1   <<<dim3((NN+3)/4), b256, 0, stream>>>(h1b, as1, ad1, b1, offs, csr, h1o);
    k_gemm2  <<<dim3((NN+63)/64), b256, 0, stream>>>(h1o, W2, as2w, ad2w, h2b, as2, ad2);
    k_agg2   <<<dim3((NN+3)/4), b256, 0, stream>>>(h2b, as2, ad2, b2, offs, csr, batch, pool);
    k_mlp    <<<dim3(NG), dim3(128), 0, stream>>>(pool, batch, l1w, l1b, l2w, l2b, out);
}

// Round 14
// 358.449 us; speedup vs baseline: 1.4391x; 1.0204x over previous
//
#include <hip/hip_runtime.h>
#include <hip/hip_bf16.h>
#include <math.h>

#define NN 50000
#define NE 800000
#define NG 64
#define INC 128
#define HIDC 64
#define NH 4
#define HC1 256
#define NEG 0.2f
#define NB 256
#define CE (NE/NB)          // 3125 edges per hist block
#define NW (NN/2)           // 25000 packed u16-pair words

typedef __attribute__((ext_vector_type(8))) short bf16x8;
typedef __attribute__((ext_vector_type(4))) float f32x4;

static __device__ __forceinline__ float lrelu(float x){ return x > 0.f ? x : NEG*x; }
static __device__ __forceinline__ float eluf(float x){ return x > 0.f ? x : expm1f(x); }
static __device__ __forceinline__ unsigned short f2bf(float x){
    unsigned u = __float_as_uint(x);
    unsigned r = u + 0x7fffu + ((u>>16)&1u);
    return (unsigned short)(r>>16);
}
static __device__ __forceinline__ float bf2f(unsigned short b){
    return __uint_as_float(((unsigned)b) << 16);
}

// ---------------- weight prep: W1T[n][k]=bf16(W1[k][n]), W2T[n][k]=bf16(W2[k][n]) ----------------
__global__ __launch_bounds__(256) void k_prepw(const float* __restrict__ W1, const float* __restrict__ W2,
                                               unsigned short* __restrict__ W1T, unsigned short* __restrict__ W2T)
{
    int i = blockIdx.x*256 + threadIdx.x;
    if (i < INC*HC1){ int k = i / HC1, n = i % HC1; W1T[n*INC + k] = f2bf(W1[i]); }
    if (i < HC1*HIDC){ int k = i / HIDC, n = i % HIDC; W2T[n*HC1 + k] = f2bf(W2[i]); }
}

// ---------------- Phase A: per-block-chunk histogram (LDS, packed 2xu16) ----------------
__global__ __launch_bounds__(256) void k_hist(const int* __restrict__ ei, unsigned* __restrict__ hist)
{
    __shared__ unsigned h[NW];          // 100 KB
    int tid = threadIdx.x, b = blockIdx.x;
    for (int w = tid; w < NW; w += 256) h[w] = 0u;
    __syncthreads();
    const int* dsts = ei + NE + b*CE;
    for (int i = tid; i < CE; i += 256){
        int d = dsts[i];
        atomicAdd(&h[d>>1], 1u << (16*(d&1)));
    }
    __syncthreads();
    unsigned* out = hist + (size_t)b*NW;
    for (int w = tid; w < NW; w += 256) out[w] = h[w];
}

// ---------------- Phase B: column scan over blocks -> per-block u16 bases + node degree ----------------
__global__ __launch_bounds__(256) void k_colscan(const unsigned* __restrict__ hist,
                                                 unsigned short* __restrict__ bases,
                                                 int* __restrict__ deg)
{
    int n = blockIdx.x*256 + threadIdx.x;
    if (n >= NN) return;
    int w = n>>1, sh = 16*(n&1);
    unsigned run = 0;
    #pragma unroll 8
    for (int b = 0; b < NB; b++){
        unsigned c = (hist[(size_t)b*NW + w] >> sh) & 0xffffu;
        bases[(size_t)b*NN + n] = (unsigned short)run;
        run += c;
    }
    deg[n] = (int)run;
}

// ---------------- exclusive scan (3 kernels) ----------------
__global__ void k_scanA(const int* __restrict__ cnt, int* __restrict__ offs, int* __restrict__ bsum)
{
    __shared__ int s[256];
    int t = threadIdx.x;
    int i = blockIdx.x*256 + t;
    int v = (i < NN) ? cnt[i] : 0;
    s[t] = v; __syncthreads();
    #pragma unroll
    for (int d=1; d<256; d<<=1){
        int tv = (t>=d)? s[t-d] : 0; __syncthreads();
        s[t] += tv; __syncthreads();
    }
    if (i < NN) offs[i] = s[t] - v;
    if (t == 255) bsum[blockIdx.x] = s[255];
}

__global__ void k_scanB(int* __restrict__ bsum, int nb)
{
    __shared__ int s[256];
    int t = threadIdx.x;
    int v = (t < nb) ? bsum[t] : 0;
    s[t] = v; __syncthreads();
    #pragma unroll
    for (int d=1; d<256; d<<=1){
        int tv = (t>=d)? s[t-d] : 0; __syncthreads();
        s[t] += tv; __syncthreads();
    }
    if (t < nb) bsum[t] = s[t] - v;
}

__global__ void k_scanC(const int* __restrict__ bsum, int* __restrict__ offs)
{
    int t = threadIdx.x;
    int i = blockIdx.x*256 + t;
    if (i < NN) offs[i] += bsum[blockIdx.x];
    if (i == 0 && blockIdx.x == 0) offs[NN] = NE;
}

// ---------------- Phase C: place edges (LDS running rank, no global atomics) ----------------
__global__ __launch_bounds__(256) void k_place(const int* __restrict__ ei,
                                               const int* __restrict__ offs,
                                               const unsigned short* __restrict__ bases,
                                               int* __restrict__ csr)
{
    __shared__ unsigned h[NW];          // running ranks, packed
    int tid = threadIdx.x, b = blockIdx.x;
    for (int w = tid; w < NW; w += 256) h[w] = 0u;
    __syncthreads();
    const int* srcs = ei + b*CE;
    const int* dsts = ei + NE + b*CE;
    const unsigned short* myb = bases + (size_t)b*NN;
    for (int i = tid; i < CE; i += 256){
        int s = srcs[i], d = dsts[i];
        unsigned old = atomicAdd(&h[d>>1], 1u << (16*(d&1)));
        unsigned rank = (old >> (16*(d&1))) & 0xffffu;
        csr[(unsigned)offs[d] + (unsigned)myb[d] + rank] = s;
    }
}

// ---------------- GEMM1 (MFMA bf16): h1 = x@W1, fused alpha_src/alpha_dst ----------------
// block = 64 rows x 256 cols, 4 waves x 16 rows. A: x fp32 -> bf16 in-reg. B: W1T (pre-transposed bf16).
// Fragments: A row=lane&15, k=(lane>>4)*8+j ; B col=lane&15, same k ; C/D col=lane&15, row=(lane>>4)*4+reg.
__global__ __launch_bounds__(256) void k_gemm1m(
    const float* __restrict__ x, const unsigned short* __restrict__ W1T,
    const float* __restrict__ aw_s, const float* __restrict__ aw_d,
    unsigned short* __restrict__ h1b, float* __restrict__ as1, float* __restrict__ ad1)
{
    int w = threadIdx.x >> 6, lane = threadIdx.x & 63;
    int r0 = blockIdx.x*64 + w*16;
    int l15 = lane & 15, lk = (lane >> 4)*8;
    int arow = r0 + l15;
    int la = arow < NN ? arow : NN-1;
    const float* ap = x + (size_t)la*INC + lk;
    const unsigned short* bt = W1T + l15*INC + lk;
    f32x4 acc[16];
    #pragma unroll
    for (int t=0;t<16;t++){ acc[t][0]=0.f; acc[t][1]=0.f; acc[t][2]=0.f; acc[t][3]=0.f; }
    #pragma unroll
    for (int kc = 0; kc < 4; kc++){
        float4 a01 = *(const float4*)(ap + kc*32);
        float4 a23 = *(const float4*)(ap + kc*32 + 4);
        bf16x8 af;
        af[0]=(short)f2bf(a01.x); af[1]=(short)f2bf(a01.y);
        af[2]=(short)f2bf(a01.z); af[3]=(short)f2bf(a01.w);
        af[4]=(short)f2bf(a23.x); af[5]=(short)f2bf(a23.y);
        af[6]=(short)f2bf(a23.z); af[7]=(short)f2bf(a23.w);
        #pragma unroll
        for (int nt = 0; nt < 16; nt++){
            bf16x8 bfr = *(const bf16x8*)(bt + nt*16*INC + kc*32);
            acc[nt] = __builtin_amdgcn_mfma_f32_16x16x32_bf16(af, bfr, acc[nt], 0, 0, 0);
        }
    }
    int g = lane >> 4;
    int crow0 = r0 + g*4;
    #pragma unroll
    for (int r = 0; r < 4; r++){
        int row = crow0 + r;
        bool ok = row < NN;
        float ps[4] = {0.f,0.f,0.f,0.f}, pd[4] = {0.f,0.f,0.f,0.f};
        #pragma unroll
        for (int nt = 0; nt < 16; nt++){
            int col = nt*16 + l15;
            float v = acc[nt][r];
            if (ok) h1b[(size_t)row*HC1 + col] = f2bf(v);
            ps[nt>>2] += v * aw_s[col];
            pd[nt>>2] += v * aw_d[col];
        }
        #pragma unroll
        for (int h = 0; h < 4; h++){
            float s = ps[h], d = pd[h];
            s += __shfl_xor(s,1); s += __shfl_xor(s,2); s += __shfl_xor(s,4); s += __shfl_xor(s,8);
            d += __shfl_xor(d,1); d += __shfl_xor(d,2); d += __shfl_xor(d,4); d += __shfl_xor(d,8);
            if (ok && l15 == 0){ as1[row*4 + h] = s; ad1[row*4 + h] = d; }
        }
    }
}

// ---------------- aggregation layer 1: hoisted weights + byte-offsets, end-reduced ssum ----------------
__global__ __launch_bounds__(256) void k_agg1(
    const unsigned short* __restrict__ h1b, const float* __restrict__ as1, const float* __restrict__ ad1,
    const float* __restrict__ b1, const int* __restrict__ offs, const int* __restrict__ csr,
    float* __restrict__ h1o)
{
    int node = blockIdx.x*4 + (threadIdx.x>>6);
    if (node >= NN) return;
    int lane = threadIdx.x & 63;
    int hd = lane >> 4;
    float adv_l = ad1[node*4 + (lane&3)];   // head (lane&3) dst-logit, for hoisted p
    const char* hp = (const char*)h1b;
    int lb = lane*8;                        // this lane's byte offset within a row
    float4 acc; acc.x=acc.y=acc.z=acc.w=0.f;
    float psum_l = 0.f;
    int base = offs[node], end = offs[node+1];
    for (int pos = base; pos < end; pos += 64){
        int nchunk = end - pos; if (nchunk > 64) nchunk = 64;
        int boff_l = ((lane < nchunk) ? csr[pos + lane] : 0) << 9;  // src*512B
        for (int sc = 0; sc*16 < nchunk; sc++){
            int srcv_off = __shfl(boff_l, sc*16 + (lane>>2));
            float p_l = 0.f;
            if (sc*16 + (lane>>2) < nchunk){
                float asv = as1[(srcv_off >> 7) + (lane&3)];  // src*4 + head
                p_l = expf(lrelu(asv + adv_l));
            }
            psum_l += p_l;
            int m = nchunk - sc*16; if (m > 16) m = 16;
            if (m == 16){
                #pragma unroll
                for (int j=0;j<16;j++){
                    int so = __shfl(boff_l, sc*16 + j);
                    float pj = __shfl(p_l, 4*j + hd);
                    ushort4 hb = *(const ushort4*)(hp + so + lb);
                    acc.x = fmaf(pj, bf2f(hb.x), acc.x);
                    acc.y = fmaf(pj, bf2f(hb.y), acc.y);
                    acc.z = fmaf(pj, bf2f(hb.z), acc.z);
                    acc.w = fmaf(pj, bf2f(hb.w), acc.w);
                }
            } else {
                for (int j=0;j<m;j++){
                    int so = __shfl(boff_l, sc*16 + j);
                    float pj = __shfl(p_l, 4*j + hd);
                    ushort4 hb = *(const ushort4*)(hp + so + lb);
                    acc.x = fmaf(pj, bf2f(hb.x), acc.x);
                    acc.y = fmaf(pj, bf2f(hb.y), acc.y);
                    acc.z = fmaf(pj, bf2f(hb.z), acc.z);
                    acc.w = fmaf(pj, bf2f(hb.w), acc.w);
                }
            }
        }
    }
    float s = psum_l;
    s += __shfl_xor(s, 4); s += __shfl_xor(s, 8);
    s += __shfl_xor(s, 16); s += __shfl_xor(s, 32);
    float ssum = __shfl(s, hd);
    {   // self loop (head hd)
        float p = expf(lrelu(as1[node*4 + hd] + ad1[node*4 + hd]));
        ssum += p;
        ushort4 hb = *(const ushort4*)(hp + (node << 9) + lb);
        acc.x = fmaf(p, bf2f(hb.x), acc.x);
        acc.y = fmaf(p, bf2f(hb.y), acc.y);
        acc.z = fmaf(p, bf2f(hb.z), acc.z);
        acc.w = fmaf(p, bf2f(hb.w), acc.w);
    }
    float inv = 1.f/(ssum + 1e-16f);
    float4 bv = ((const float4*)b1)[lane];
    float4 o;
    o.x = eluf(fmaf(acc.x, inv, bv.x));
    o.y = eluf(fmaf(acc.y, inv, bv.y));
    o.z = eluf(fmaf(acc.z, inv, bv.z));
    o.w = eluf(fmaf(acc.w, inv, bv.w));
    ((float4*)h1o)[(size_t)node*64 + lane] = o;
}

// ---------------- GEMM2 (MFMA bf16): h2 = h1o@W2, fused alpha (1 head) ----------------
__global__ __launch_bounds__(256) void k_gemm2m(
    const float* __restrict__ h1o, const unsigned short* __restrict__ W2T,
    const float* __restrict__ aw_s, const float* __restrict__ aw_d,
    unsigned short* __restrict__ h2b, float* __restrict__ as2, float* __restrict__ ad2)
{
    int w = threadIdx.x >> 6, lane = threadIdx.x & 63;
    int r0 = blockIdx.x*64 + w*16;
    int l15 = lane & 15, lk = (lane >> 4)*8;
    int arow = r0 + l15;
    int la = arow < NN ? arow : NN-1;
    const float* ap = h1o + (size_t)la*HC1 + lk;
    const unsigned short* bt = W2T + l15*HC1 + lk;
    f32x4 acc[4];
    #pragma unroll
    for (int t=0;t<4;t++){ acc[t][0]=0.f; acc[t][1]=0.f; acc[t][2]=0.f; acc[t][3]=0.f; }
    #pragma unroll
    for (int kc = 0; kc < 8; kc++){
        float4 a01 = *(const float4*)(ap + kc*32);
        float4 a23 = *(const float4*)(ap + kc*32 + 4);
        bf16x8 af;
        af[0]=(short)f2bf(a01.x); af[1]=(short)f2bf(a01.y);
        af[2]=(short)f2bf(a01.z); af[3]=(short)f2bf(a01.w);
        af[4]=(short)f2bf(a23.x); af[5]=(short)f2bf(a23.y);
        af[6]=(short)f2bf(a23.z); af[7]=(short)f2bf(a23.w);
        #pragma unroll
        for (int nt = 0; nt < 4; nt++){
            bf16x8 bfr = *(const bf16x8*)(bt + nt*16*HC1 + kc*32);
            acc[nt] = __builtin_amdgcn_mfma_f32_16x16x32_bf16(af, bfr, acc[nt], 0, 0, 0);
        }
    }
    int g = lane >> 4;
    int crow0 = r0 + g*4;
    #pragma unroll
    for (int r = 0; r < 4; r++){
        int row = crow0 + r;
        bool ok = row < NN;
        float ps = 0.f, pd = 0.f;
        #pragma unroll
        for (int nt = 0; nt < 4; nt++){
            int col = nt*16 + l15;
            float v = acc[nt][r];
            if (ok) h2b[(size_t)row*HIDC + col] = f2bf(v);
            ps += v * aw_s[col];
            pd += v * aw_d[col];
        }
        ps += __shfl_xor(ps,1); ps += __shfl_xor(ps,2); ps += __shfl_xor(ps,4); ps += __shfl_xor(ps,8);
        pd += __shfl_xor(pd,1); pd += __shfl_xor(pd,2); pd += __shfl_xor(pd,4); pd += __shfl_xor(pd,8);
        if (ok && l15 == 0){ as2[row] = ps; ad2[row] = pd; }
    }
}

// ---------------- aggregation layer 2: r8 structure + trims + block LDS pool combine ----------------
__global__ __launch_bounds__(256) void k_agg2(
    const unsigned short* __restrict__ h2b, const float* __restrict__ as2, const float* __restrict__ ad2,
    const float* __restrict__ b2, const int* __restrict__ offs, const int* __restrict__ csr,
    const int* __restrict__ batch, float* __restrict__ pool)
{
    __shared__ float pacc[4][64];
    __shared__ int gs[4];
    int tid = threadIdx.x;
    int wid = tid >> 6;
    int lane = tid & 63;
    int node = blockIdx.x*4 + wid;        // NN % 4 == 0: always valid
    float adv = ad2[node];
    const char* hp = (const char*)h2b;
    int lb = lane*2;
    float accv = 0.f, psum_l = 0.f;
    int base = offs[node], end = offs[node+1];
    for (int pos = base; pos < end; pos += 64){
        int nchunk = end - pos; if (nchunk > 64) nchunk = 64;
        int boff_l = 0; float p_l = 0.f;
        if (lane < nchunk){
            int src_l = csr[pos + lane];
            boff_l = src_l << 7;                    // src*128B
            p_l = expf(lrelu(as2[src_l] + adv));    // hoisted: one exp per edge
        }
        psum_l += p_l;
        for (int sc = 0; sc*16 < nchunk; sc++){
            int m = nchunk - sc*16; if (m > 16) m = 16;
            if (m == 16){
                #pragma unroll
                for (int j=0;j<16;j++){
                    int jj = sc*16 + j;
                    int so = __shfl(boff_l, jj);
                    float pj = __shfl(p_l, jj);
                    accv = fmaf(pj, bf2f(*(const unsigned short*)(hp + so + lb)), accv);
                }
            } else {
                for (int j=0;j<m;j++){
                    int jj = sc*16 + j;
                    int so = __shfl(boff_l, jj);
                    float pj = __shfl(p_l, jj);
                    accv = fmaf(pj, bf2f(*(const unsigned short*)(hp + so + lb)), accv);
                }
            }
        }
    }
    float ssum = psum_l;
    ssum += __shfl_xor(ssum, 1); ssum += __shfl_xor(ssum, 2);
    ssum += __shfl_xor(ssum, 4); ssum += __shfl_xor(ssum, 8);
    ssum += __shfl_xor(ssum, 16); ssum += __shfl_xor(ssum, 32);
    {   // self loop
        float p = expf(lrelu(as2[node] + adv));
        ssum += p;
        accv = fmaf(p, bf2f(*(const unsigned short*)(hp + (node << 7) + lb)), accv);
    }
    float o = eluf(accv/(ssum + 1e-16f) + b2[lane]);
    int g = batch[node];
    pacc[wid][lane] = o;
    if (lane == 0) gs[wid] = g;
    __syncthreads();
    if (gs[0] == gs[1] && gs[1] == gs[2] && gs[2] == gs[3]){
        if (wid == 0){
            float s = (pacc[0][lane] + pacc[1][lane]) + (pacc[2][lane] + pacc[3][lane]);
            atomicAdd(&pool[g*HIDC + lane], s);
        }
    } else {
        atomicAdd(&pool[g*HIDC + lane], o);   // rare graph-boundary block
    }
}

// ---------------- final MLP head (gcnt folded in), one block per graph ----------------
__global__ __launch_bounds__(128) void k_mlp(
    const float* __restrict__ pool, const int* __restrict__ batch,
    const float* __restrict__ l1w, const float* __restrict__ l1b,
    const float* __restrict__ l2w, const float* __restrict__ l2b,
    float* __restrict__ out)
{
    __shared__ float pl[64];
    __shared__ float wsum[2];
    int g = blockIdx.x, t = threadIdx.x;
    int lo = 0, hi = NN;
    while (lo < hi){ int mid = (lo+hi)>>1; if (batch[mid] < g) lo = mid+1; else hi = mid; }
    int a = lo;
    lo = 0; hi = NN;
    while (lo < hi){ int mid = (lo+hi)>>1; if (batch[mid] < g+1) lo = mid+1; else hi = mid; }
    float inv = 1.f / fmaxf((float)(lo - a), 1.f);
    if (t < 64) pl[t] = pool[g*64 + t] * inv;
    __syncthreads();
    float z = l1b[t];
    #pragma unroll 8
    for (int c=0;c<64;c++) z = fmaf(pl[c], l1w[c*128 + t], z);
    z = fmaxf(z, 0.f);
    float part = z * l2w[t];
    #pragma unroll
    for (int d=1; d<64; d<<=1) part += __shfl_xor(part, d);
    if ((t & 63) == 0) wsum[t>>6] = part;
    __syncthreads();
    if (t == 0) out[g] = wsum[0] + wsum[1] + l2b[0];
}

extern "C" void kernel_launch(void* const* d_in, const int* in_sizes, int n_in,
                              void* d_out, int out_size, void* d_ws, size_t ws_size,
                              hipStream_t stream) {
    const float* x    = (const float*)d_in[0];
    const int*   ei   = (const int*)d_in[1];
    const int*   batch= (const int*)d_in[2];
    const float* W1   = (const float*)d_in[3];
    const float* as1w = (const float*)d_in[4];
    const float* ad1w = (const float*)d_in[5];
    const float* b1   = (const float*)d_in[6];
    const float* W2   = (const float*)d_in[7];
    const float* as2w = (const float*)d_in[8];
    const float* ad2w = (const float*)d_in[9];
    const float* b2   = (const float*)d_in[10];
    const float* l1w  = (const float*)d_in[11];
    const float* l1b  = (const float*)d_in[12];
    const float* l2w  = (const float*)d_in[13];
    const float* l2b  = (const float*)d_in[14];
    float* out = (float*)d_out;

    char* ws = (char*)d_ws;
    size_t off = 0;
    auto alloc = [&](size_t bytes) -> void* {
        void* p = ws + off; off += (bytes + 255) & ~(size_t)255; return p;
    };
    unsigned short* h1b = (unsigned short*)alloc((size_t)NN*HC1*2);  // bf16 h1
    float* h1o  = (float*)alloc((size_t)NN*HC1*4);
    unsigned short* h2b = (unsigned short*)h1b;   // alias: h1 dead after k_agg1
    // CSR-build scratch aliases h1o (dead until k_agg1 writes it):
    unsigned* hist = (unsigned*)h1o;                       // 256*25000*4 = 25.6 MB
    unsigned short* bases = (unsigned short*)((char*)h1o + (size_t)NB*NW*4); // 25.6 MB
    float* as1  = (float*)alloc((size_t)NN*4*4);
    float* ad1  = (float*)alloc((size_t)NN*4*4);
    float* as2  = (float*)alloc((size_t)NN*4);
    float* ad2  = (float*)alloc((size_t)NN*4);
    int*   deg  = (int*)alloc((size_t)NN*4);
    float* pool = (float*)alloc((size_t)NG*HIDC*4);
    int*   offs = (int*)alloc((size_t)(NN+16)*4);
    int*   bsum = (int*)alloc((size_t)256*4);
    int*   csr  = (int*)alloc((size_t)NE*4);
    unsigned short* W1T = (unsigned short*)alloc((size_t)HC1*INC*2);   // 256x128 bf16
    unsigned short* W2T = (unsigned short*)alloc((size_t)HIDC*HC1*2);  // 64x256 bf16
    (void)ws_size; (void)in_sizes; (void)n_in; (void)out_size;

    hipMemsetAsync(pool, 0, (size_t)NG*HIDC*4, stream);

    dim3 b256(256);
    int nb = (NN + 255)/256;
    k_prepw  <<<dim3(128), b256, 0, stream>>>(W1, W2, W1T, W2T);
    k_hist   <<<dim3(NB), b256, 0, stream>>>(ei, hist);
    k_colscan<<<dim3(nb), b256, 0, stream>>>(hist, bases, deg);
    k_scanA  <<<dim3(nb), b256, 0, stream>>>(deg, offs, bsum);
    k_scanB  <<<dim3(1), b256, 0, stream>>>(bsum, nb);
    k_scanC  <<<dim3(nb), b256, 0, stream>>>(bsum, offs);
    k_place  <<<dim3(NB), b256, 0, stream>>>(ei, offs, bases, csr);
    k_gemm1m <<<dim3((NN+63)/64), b256, 0, stream>>>(x, W1T, as1w, ad1w, h1b, as1, ad1);
    k_agg1   <<<dim3((NN+3)/4), b256, 0, stream>>>(h1b, as1, ad1, b1, offs, csr, h1o);
    k_gemm2m <<<dim3((NN+63)/64), b256, 0, stream>>>(h1o, W2T, as2w, ad2w, h2b, as2, ad2);
    k_agg2   <<<dim3((NN+3)/4), b256, 0, stream>>>(h2b, as2, ad2, b2, offs, csr, batch, pool);
    k_mlp    <<<dim3(NG), dim3(128), 0, stream>>>(pool, batch, l1w, l1b, l2w, l2b, out);
}